// Round 1
// baseline (249.661 us; speedup 1.0000x reference)
//
#include <hip/hip_runtime.h>

typedef _Float16 f16;
typedef _Float16 f16x8 __attribute__((ext_vector_type(8)));
typedef _Float16 f16x4 __attribute__((ext_vector_type(4)));
typedef float f32x4 __attribute__((ext_vector_type(4)));

#define SCALE_Q 0.125f   // HEAD_DIM=64 -> 64^-0.5

__device__ __forceinline__ f32x4 mfma16x16x32(f16x8 a, f16x8 b, f32x4 c) {
  return __builtin_amdgcn_mfma_f32_16x16x32_f16(a, b, c, 0, 0, 0);
}

typedef const __attribute__((address_space(1))) void* gptr1;
typedef __attribute__((address_space(3))) void* lptr3;
__device__ __forceinline__ void gload_lds16(const void* g, void* l) {
  __builtin_amdgcn_global_load_lds((gptr1)g, (lptr3)l, 16, 0, 0);
}

// ---------------- f32 -> f16 elementwise convert (x) ----------------
__global__ __launch_bounds__(256)
void cvt_f32_f16(const float* __restrict__ in, f16* __restrict__ out, int n4) {
  int i = blockIdx.x * 256 + threadIdx.x;
  if (i >= n4) return;
  float4 v = reinterpret_cast<const float4*>(in)[i];
  f16x4 o = {(f16)v.x, (f16)v.y, (f16)v.z, (f16)v.w};
  reinterpret_cast<f16x4*>(out)[i] = o;
}

// ---------------- transpose + convert: in[R][Cin] f32 -> out[Cin][R] f16 ----------------
__global__ __launch_bounds__(256)
void transpose_cvt(const float* __restrict__ in, f16* __restrict__ out, int R, int Cin) {
  __shared__ float tile[32][33];
  int bx = blockIdx.x * 32;  // col block in input
  int by = blockIdx.y * 32;  // row block in input
  int tx = threadIdx.x & 31, ty = threadIdx.x >> 5;
#pragma unroll
  for (int i = ty; i < 32; i += 8)
    tile[i][tx] = in[(size_t)(by + i) * Cin + bx + tx];
  __syncthreads();
#pragma unroll
  for (int i = ty; i < 32; i += 8)
    out[(size_t)(bx + i) * R + by + tx] = (f16)tile[tx][i];
}

// ---------------- GEMM: C[M][N] = A[M][K] * Bt[N][K]^T, fused epilogue ----------------
// QKV_EPI: out = f16(acc + bias[n]), cols < 1024 (=Q) scaled by SCALE_Q
// else:    out = f32(acc + bias[n])
template<bool QKV_EPI>
__global__ __launch_bounds__(256)
void gemm_bt(const f16* __restrict__ A, const f16* __restrict__ Bt,
             const float* __restrict__ bias, f16* __restrict__ outh,
             float* __restrict__ outf, int M, int N, int K) {
  constexpr int BM = 128, BN = 128, BK = 32;
  __shared__ f16 As[BM * BK];
  __shared__ f16 Bs[BN * BK];
  const int tid = threadIdx.x;
  const int l = tid & 63;
  const int w = tid >> 6;
  const int wr = w >> 1, wc = w & 1;
  const int bm = blockIdx.x * BM, bn = blockIdx.y * BN;
  const int l15 = l & 15, lhi = l >> 4;

  f32x4 acc[4][4] = {};

  const char* Ab = (const char*)A;
  const char* Bb = (const char*)Bt;
  const size_t rowbytes = (size_t)K * 2;

  for (int kt = 0; kt < K; kt += BK) {
    __syncthreads();
#pragma unroll
    for (int c = 0; c < 2; ++c) {
      int o = tid * 16 + c * 4096;     // byte offset into 8192B tile
      int r = o >> 6;                  // tile row (64B per row of 32 f16)
      int cb = o & 63;                 // byte within row
      gload_lds16(Ab + (size_t)(bm + r) * rowbytes + (size_t)kt * 2 + cb, (char*)As + o);
      gload_lds16(Bb + (size_t)(bn + r) * rowbytes + (size_t)kt * 2 + cb, (char*)Bs + o);
    }
    __syncthreads();   // drains vmcnt(0) for global_load_lds

    f16x8 af[4], bf[4];
#pragma unroll
    for (int i = 0; i < 4; ++i)
      af[i] = *reinterpret_cast<const f16x8*>(&As[(wr * 64 + i * 16 + l15) * BK + 8 * lhi]);
#pragma unroll
    for (int i = 0; i < 4; ++i)
      bf[i] = *reinterpret_cast<const f16x8*>(&Bs[(wc * 64 + i * 16 + l15) * BK + 8 * lhi]);
#pragma unroll
    for (int i = 0; i < 4; ++i)
#pragma unroll
      for (int j = 0; j < 4; ++j)
        acc[i][j] = mfma16x16x32(af[i], bf[j], acc[i][j]);
  }

#pragma unroll
  for (int i = 0; i < 4; ++i) {
#pragma unroll
    for (int j = 0; j < 4; ++j) {
      int gr0 = bm + wr * 64 + i * 16 + 4 * lhi;
      int gc = bn + wc * 64 + j * 16 + l15;
      float b = bias[gc];
#pragma unroll
      for (int r = 0; r < 4; ++r) {
        float v = acc[i][j][r] + b;
        if constexpr (QKV_EPI) {
          if (gc < 1024) v *= SCALE_Q;
          outh[(size_t)(gr0 + r) * N + gc] = (f16)v;
        } else {
          outf[(size_t)(gr0 + r) * N + gc] = v;
        }
      }
    }
  }
}

// ---------------- flash attention ----------------
// qkv[4096][3072] f16: row = b*2048+t; cols [0,1024)=Q(pre-scaled), [1024,2048)=K, [2048,3072)=V
// out: attnh[4096][1024] f16, col = h*64+d
__global__ __launch_bounds__(256)
void attn_kernel(const f16* __restrict__ qkv, f16* __restrict__ outh) {
  constexpr int T = 2048;
  constexpr int ROW = 3072;
  __shared__ f16 Vt[64 * 64];      // [d][key] transposed V tile
  __shared__ f16 Pb[4][16 * 64];   // per-wave P scratch [qrow][key]

  const int tid = threadIdx.x;
  const int l = tid & 63;
  const int w = tid >> 6;
  const int l15 = l & 15, lhi = l >> 4;

  const int bid = blockIdx.x;
  const int qt = bid & 31;
  const int h = (bid >> 5) & 15;
  const int b = bid >> 9;

  const size_t base = (size_t)b * T * ROW;
  const int t0 = qt * 64 + w * 16;  // this wave's first q row (within batch b)

  // hoist Q fragments (already scaled by SCALE_Q in GEMM1 epilogue)
  f16x8 qa0, qa1;
  {
    const f16* qp = qkv + base + (size_t)(t0 + l15) * ROW + h * 64 + 8 * lhi;
    qa0 = *reinterpret_cast<const f16x8*>(qp);
    qa1 = *reinterpret_cast<const f16x8*>(qp + 32);
  }

  f32x4 oa[4] = {};
  float m_r[4] = {-1e30f, -1e30f, -1e30f, -1e30f};
  float l_r[4] = {0.f, 0.f, 0.f, 0.f};

  const f16* Kb = qkv + base + 1024 + h * 64;
  const f16* Vb = qkv + base + 2048 + h * 64;

  const int vt_t = tid & 63;
  const int vt_d0 = (tid >> 6) * 16;

  for (int kv = 0; kv < T; kv += 64) {
    __syncthreads();  // previous tile's compute done before restaging Vt
    {
      const f16* vp = Vb + (size_t)(kv + vt_t) * ROW + vt_d0;
      f16x8 v0 = *reinterpret_cast<const f16x8*>(vp);
      f16x8 v1 = *reinterpret_cast<const f16x8*>(vp + 8);
#pragma unroll
      for (int j = 0; j < 8; ++j) {
        Vt[(vt_d0 + j) * 64 + vt_t] = v0[j];       // conflict-free: lanes -> consecutive keys
        Vt[(vt_d0 + 8 + j) * 64 + vt_t] = v1[j];
      }
    }
    __syncthreads();

    // S = Q K^T  (K fragments straight from global; L2-resident)
    f32x4 s[4];
#pragma unroll
    for (int kc = 0; kc < 4; ++kc) {
      const f16* kp = Kb + (size_t)(kv + kc * 16 + l15) * ROW + 8 * lhi;
      f16x8 k0 = *reinterpret_cast<const f16x8*>(kp);
      f16x8 k1 = *reinterpret_cast<const f16x8*>(kp + 32);
      f32x4 z = {};
      z = mfma16x16x32(qa0, k0, z);
      z = mfma16x16x32(qa1, k1, z);
      s[kc] = z;
    }

    // online softmax: row m = 4*lhi + i lives in one 16-lane group, 16 keys/lane-chunk
    float p[4][4];
    float scl[4];
#pragma unroll
    for (int i = 0; i < 4; ++i) {
      float tm = fmaxf(fmaxf(s[0][i], s[1][i]), fmaxf(s[2][i], s[3][i]));
      tm = fmaxf(tm, __shfl_xor(tm, 1));
      tm = fmaxf(tm, __shfl_xor(tm, 2));
      tm = fmaxf(tm, __shfl_xor(tm, 4));
      tm = fmaxf(tm, __shfl_xor(tm, 8));
      float mnew = fmaxf(m_r[i], tm);
      float sc = __expf(m_r[i] - mnew);
      float rs = 0.f;
#pragma unroll
      for (int kc = 0; kc < 4; ++kc) {
        float pv = __expf(s[kc][i] - mnew);
        p[i][kc] = pv;
        rs += pv;
      }
      rs += __shfl_xor(rs, 1);
      rs += __shfl_xor(rs, 2);
      rs += __shfl_xor(rs, 4);
      rs += __shfl_xor(rs, 8);
      l_r[i] = l_r[i] * sc + rs;
      m_r[i] = mnew;
      scl[i] = sc;
    }

#pragma unroll
    for (int nc = 0; nc < 4; ++nc)
#pragma unroll
      for (int i = 0; i < 4; ++i)
        oa[nc][i] *= scl[i];

    // P (D-layout) -> LDS -> A-layout fragments
    f16* pb = &Pb[w][0];
#pragma unroll
    for (int i = 0; i < 4; ++i) {
      int m = 4 * lhi + i;
#pragma unroll
      for (int kc = 0; kc < 4; ++kc)
        pb[m * 64 + kc * 16 + l15] = (f16)p[i][kc];
    }
    f16x8 pa0 = *reinterpret_cast<const f16x8*>(&pb[l15 * 64 + 8 * lhi]);
    f16x8 pa1 = *reinterpret_cast<const f16x8*>(&pb[l15 * 64 + 32 + 8 * lhi]);

    // O += P V
#pragma unroll
    for (int nc = 0; nc < 4; ++nc) {
      f16x8 v0 = *reinterpret_cast<const f16x8*>(&Vt[(nc * 16 + l15) * 64 + 8 * lhi]);
      f16x8 v1 = *reinterpret_cast<const f16x8*>(&Vt[(nc * 16 + l15) * 64 + 32 + 8 * lhi]);
      oa[nc] = mfma16x16x32(pa0, v0, oa[nc]);
      oa[nc] = mfma16x16x32(pa1, v1, oa[nc]);
    }
  }

  const int orow0 = b * T + t0;
#pragma unroll
  for (int nc = 0; nc < 4; ++nc) {
#pragma unroll
    for (int i = 0; i < 4; ++i) {
      int m = 4 * lhi + i;
      float inv = 1.0f / l_r[i];
      outh[(size_t)(orow0 + m) * 1024 + h * 64 + nc * 16 + l15] = (f16)(oa[nc][i] * inv);
    }
  }
}

extern "C" void kernel_launch(void* const* d_in, const int* in_sizes, int n_in,
                              void* d_out, int out_size, void* d_ws, size_t ws_size,
                              hipStream_t stream) {
  const float* x      = (const float*)d_in[0];  // [2,2048,1024]
  const float* w_qkv  = (const float*)d_in[1];  // [1024,3072]
  const float* b_qkv  = (const float*)d_in[2];  // [3072]
  const float* w_out  = (const float*)d_in[3];  // [1024,1024]
  const float* b_out  = (const float*)d_in[4];  // [1024]
  float* out = (float*)d_out;                   // [2,2048,1024] f32

  char* ws = (char*)d_ws;
  f16* xh    = (f16*)(ws);                 //  8 MB: x as f16 [4096][1024]
  f16* wqkvT = (f16*)(ws + 8388608);       //  6 MB: w_qkv^T [3072][1024]
  f16* woutT = (f16*)(ws + 14680064);      //  2 MB: w_out^T [1024][1024]
  f16* qkvh  = (f16*)(ws + 16777216);      // 24 MB: qkv [4096][3072] (Q pre-scaled)
  f16* attnh = (f16*)(ws + 41943040);      //  8 MB: attention out [4096][1024]

  cvt_f32_f16<<<4096, 256, 0, stream>>>(x, xh, 1048576);
  transpose_cvt<<<dim3(96, 32), 256, 0, stream>>>(w_qkv, wqkvT, 1024, 3072);
  transpose_cvt<<<dim3(32, 32), 256, 0, stream>>>(w_out, woutT, 1024, 1024);
  gemm_bt<true><<<dim3(32, 24), 256, 0, stream>>>(xh, wqkvT, b_qkv, qkvh, nullptr,
                                                  4096, 3072, 1024);
  attn_kernel<<<1024, 256, 0, stream>>>(qkvh, attnh);
  gemm_bt<false><<<dim3(32, 8), 256, 0, stream>>>(attnh, woutT, b_out, nullptr, out,
                                                  4096, 1024, 1024);
}

// Round 2
// 232.458 us; speedup vs baseline: 1.0740x; 1.0740x over previous
//
#include <hip/hip_runtime.h>

typedef _Float16 f16;
typedef _Float16 f16x8 __attribute__((ext_vector_type(8)));
typedef _Float16 f16x4 __attribute__((ext_vector_type(4)));
typedef float f32x4 __attribute__((ext_vector_type(4)));

#define SCALE_Q 0.125f   // HEAD_DIM=64 -> 64^-0.5

__device__ __forceinline__ f32x4 mfma16x16x32(f16x8 a, f16x8 b, f32x4 c) {
  return __builtin_amdgcn_mfma_f32_16x16x32_f16(a, b, c, 0, 0, 0);
}

typedef const __attribute__((address_space(1))) void* gptr1;
typedef __attribute__((address_space(3))) void* lptr3;
__device__ __forceinline__ void gload_lds16(const void* g, void* l) {
  __builtin_amdgcn_global_load_lds((gptr1)g, (lptr3)l, 16, 0, 0);
}

// ---------------- f32 -> f16 elementwise convert (x) ----------------
__global__ __launch_bounds__(256)
void cvt_f32_f16(const float* __restrict__ in, f16* __restrict__ out, int n4) {
  int i = blockIdx.x * 256 + threadIdx.x;
  if (i >= n4) return;
  float4 v = reinterpret_cast<const float4*>(in)[i];
  f16x4 o = {(f16)v.x, (f16)v.y, (f16)v.z, (f16)v.w};
  reinterpret_cast<f16x4*>(out)[i] = o;
}

// ---------------- transpose + convert: in[R][Cin] f32 -> out[Cin][R] f16 ----------------
__global__ __launch_bounds__(256)
void transpose_cvt(const float* __restrict__ in, f16* __restrict__ out, int R, int Cin) {
  __shared__ float tile[32][33];
  int bx = blockIdx.x * 32;  // col block in input
  int by = blockIdx.y * 32;  // row block in input
  int tx = threadIdx.x & 31, ty = threadIdx.x >> 5;
#pragma unroll
  for (int i = ty; i < 32; i += 8)
    tile[i][tx] = in[(size_t)(by + i) * Cin + bx + tx];
  __syncthreads();
#pragma unroll
  for (int i = ty; i < 32; i += 8)
    out[(size_t)(bx + i) * R + by + tx] = (f16)tile[tx][i];
}

// ---------------- GEMM: C[M][N] = A[M][K] * Bt[N][K]^T, fused epilogue ----------------
template<bool QKV_EPI>
__global__ __launch_bounds__(256)
void gemm_bt(const f16* __restrict__ A, const f16* __restrict__ Bt,
             const float* __restrict__ bias, f16* __restrict__ outh,
             float* __restrict__ outf, int M, int N, int K) {
  constexpr int BM = 128, BN = 128, BK = 32;
  __shared__ f16 As[BM * BK];
  __shared__ f16 Bs[BN * BK];
  const int tid = threadIdx.x;
  const int l = tid & 63;
  const int w = tid >> 6;
  const int wr = w >> 1, wc = w & 1;
  const int bm = blockIdx.x * BM, bn = blockIdx.y * BN;
  const int l15 = l & 15, lhi = l >> 4;

  f32x4 acc[4][4] = {};

  const char* Ab = (const char*)A;
  const char* Bb = (const char*)Bt;
  const size_t rowbytes = (size_t)K * 2;

  for (int kt = 0; kt < K; kt += BK) {
    __syncthreads();
#pragma unroll
    for (int c = 0; c < 2; ++c) {
      int o = tid * 16 + c * 4096;
      int r = o >> 6;
      int cb = o & 63;
      gload_lds16(Ab + (size_t)(bm + r) * rowbytes + (size_t)kt * 2 + cb, (char*)As + o);
      gload_lds16(Bb + (size_t)(bn + r) * rowbytes + (size_t)kt * 2 + cb, (char*)Bs + o);
    }
    __syncthreads();

    f16x8 af[4], bf[4];
#pragma unroll
    for (int i = 0; i < 4; ++i)
      af[i] = *reinterpret_cast<const f16x8*>(&As[(wr * 64 + i * 16 + l15) * BK + 8 * lhi]);
#pragma unroll
    for (int i = 0; i < 4; ++i)
      bf[i] = *reinterpret_cast<const f16x8*>(&Bs[(wc * 64 + i * 16 + l15) * BK + 8 * lhi]);
#pragma unroll
    for (int i = 0; i < 4; ++i)
#pragma unroll
      for (int j = 0; j < 4; ++j)
        acc[i][j] = mfma16x16x32(af[i], bf[j], acc[i][j]);
  }

#pragma unroll
  for (int i = 0; i < 4; ++i) {
#pragma unroll
    for (int j = 0; j < 4; ++j) {
      int gr0 = bm + wr * 64 + i * 16 + 4 * lhi;
      int gc = bn + wc * 64 + j * 16 + l15;
      float b = bias[gc];
#pragma unroll
      for (int r = 0; r < 4; ++r) {
        float v = acc[i][j][r] + b;
        if constexpr (QKV_EPI) {
          if (gc < 1024) v *= SCALE_Q;
          outh[(size_t)(gr0 + r) * N + gc] = (f16)v;
        } else {
          outf[(size_t)(gr0 + r) * N + gc] = v;
        }
      }
    }
  }
}

// ---------------- flash attention (v2: L2-friendly bid, dbuf V, prefetch K, swizzled LDS) ----
// qkv[4096][3072] f16: row = b*2048+t; cols [0,1024)=Q(pre-scaled), [1024,2048)=K, [2048,3072)=V
// out: attnh[4096][1024] f16, col = h*64+d
__global__ __launch_bounds__(256)
void attn_kernel(const f16* __restrict__ qkv, f16* __restrict__ outh) {
  constexpr int T = 2048;
  constexpr int ROW = 3072;
  __shared__ f16 Vt[2][64 * 64];   // [buf][d][key] transposed V tile, XOR-swizzled
  __shared__ f16 Pb[4][16 * 64];   // per-wave P scratch [qrow][key], XOR-swizzled

  const int tid = threadIdx.x;
  const int l = tid & 63;
  const int w = tid >> 6;
  const int l15 = l & 15, lhi = l >> 4;

  // (b,h) pair in LOW bits of bid -> all 32 q-tiles of one pair land on ONE XCD,
  // whose L2 then holds that pair's 512KB K+V (4 pairs/XCD = 2MB, fits 4MB L2).
  const int bid = blockIdx.x;
  const int p = bid & 31;
  const int b = p >> 4;
  const int h = p & 15;
  const int qt = bid >> 5;

  const size_t base = (size_t)b * T * ROW;
  const int t0 = qt * 64 + w * 16;

  // hoist Q fragments (already scaled by SCALE_Q in GEMM1 epilogue)
  f16x8 qa0, qa1;
  {
    const f16* qp = qkv + base + (size_t)(t0 + l15) * ROW + h * 64 + 8 * lhi;
    qa0 = *reinterpret_cast<const f16x8*>(qp);
    qa1 = *reinterpret_cast<const f16x8*>(qp + 32);
  }

  f32x4 oa[4] = {};
  float m_r[4] = {-1e30f, -1e30f, -1e30f, -1e30f};
  float l_r[4] = {0.f, 0.f, 0.f, 0.f};

  const f16* Kb = qkv + base + 1024 + h * 64;
  const f16* Vb = qkv + base + 2048 + h * 64;

  const int vt_t = tid & 63;          // key row this thread stages
  const int vt_d0 = (tid >> 6) * 16;  // d-range this thread stages

  f16x8 kf0[4], kf1[4];   // K fragments for current tile
  f16x8 vr0, vr1;         // staged V rows for NEXT tile

#define LOADK(KV)                                                              \
  do {                                                                         \
    _Pragma("unroll") for (int kc = 0; kc < 4; ++kc) {                         \
      const f16* kp = Kb + (size_t)((KV) + kc * 16 + l15) * ROW + 8 * lhi;     \
      kf0[kc] = *reinterpret_cast<const f16x8*>(kp);                           \
      kf1[kc] = *reinterpret_cast<const f16x8*>(kp + 32);                      \
    }                                                                          \
  } while (0)

#define LOADV(KV)                                                              \
  do {                                                                         \
    const f16* vp = Vb + (size_t)((KV) + vt_t) * ROW + vt_d0;                  \
    vr0 = *reinterpret_cast<const f16x8*>(vp);                                 \
    vr1 = *reinterpret_cast<const f16x8*>(vp + 8);                             \
  } while (0)

#define WRITEV(DST)                                                            \
  do {                                                                         \
    _Pragma("unroll") for (int j = 0; j < 8; ++j) {                            \
      int r0 = vt_d0 + j, r1 = vt_d0 + 8 + j;                                  \
      (DST)[r0 * 64 + (vt_t ^ ((r0 & 7) << 3))] = vr0[j];                      \
      (DST)[r1 * 64 + (vt_t ^ ((r1 & 7) << 3))] = vr1[j];                      \
    }                                                                          \
  } while (0)

  // prologue: K(0) frags, V(0) staged into Vt[0]
  LOADK(0);
  LOADV(0);
  WRITEV(&Vt[0][0]);
  __syncthreads();

  for (int t = 0; t < 32; ++t) {
    const int kv = t * 64;
    const int nkv = (t < 31) ? kv + 64 : kv;  // clamped; last-iter loads unused
    f16* Vcur = &Vt[t & 1][0];
    f16* Vnxt = &Vt[(t & 1) ^ 1][0];

    // issue next tile's V loads early (consumed by WRITEV at bottom of this iter)
    LOADV(nkv);

    // S = Q K^T from register K fragments
    f32x4 s[4];
    __builtin_amdgcn_s_setprio(1);
#pragma unroll
    for (int kc = 0; kc < 4; ++kc) {
      f32x4 z = {};
      z = mfma16x16x32(qa0, kf0[kc], z);
      z = mfma16x16x32(qa1, kf1[kc], z);
      s[kc] = z;
    }
    __builtin_amdgcn_s_setprio(0);

    // K fragments consumed -> prefetch next tile's K into the same registers
    LOADK(nkv);

    // online softmax: row m = 4*lhi + i, 16 keys per kc chunk spread over l15
    float p_[4][4];
    float scl[4];
#pragma unroll
    for (int i = 0; i < 4; ++i) {
      float tm = fmaxf(fmaxf(s[0][i], s[1][i]), fmaxf(s[2][i], s[3][i]));
      tm = fmaxf(tm, __shfl_xor(tm, 1));
      tm = fmaxf(tm, __shfl_xor(tm, 2));
      tm = fmaxf(tm, __shfl_xor(tm, 4));
      tm = fmaxf(tm, __shfl_xor(tm, 8));
      float mnew = fmaxf(m_r[i], tm);
      float sc = __expf(m_r[i] - mnew);
      float rs = 0.f;
#pragma unroll
      for (int kc = 0; kc < 4; ++kc) {
        float pv = __expf(s[kc][i] - mnew);
        p_[i][kc] = pv;
        rs += pv;
      }
      rs += __shfl_xor(rs, 1);
      rs += __shfl_xor(rs, 2);
      rs += __shfl_xor(rs, 4);
      rs += __shfl_xor(rs, 8);
      l_r[i] = l_r[i] * sc + rs;
      m_r[i] = mnew;
      scl[i] = sc;
    }

#pragma unroll
    for (int nc = 0; nc < 4; ++nc)
#pragma unroll
      for (int i = 0; i < 4; ++i)
        oa[nc][i] *= scl[i];

    // P (D-layout) -> per-wave LDS (swizzled) -> A-layout fragments
    f16* pb = &Pb[w][0];
#pragma unroll
    for (int i = 0; i < 4; ++i) {
      int m = 4 * lhi + i;
#pragma unroll
      for (int kc = 0; kc < 4; ++kc)
        pb[m * 64 + ((kc * 16 + l15) ^ ((m & 7) << 3))] = (f16)p_[i][kc];
    }
    f16x8 pa0 = *reinterpret_cast<const f16x8*>(&pb[l15 * 64 + ((8 * lhi) ^ ((l15 & 7) << 3))]);
    f16x8 pa1 = *reinterpret_cast<const f16x8*>(&pb[l15 * 64 + ((32 + 8 * lhi) ^ ((l15 & 7) << 3))]);

    // O += P V  (swizzled Vt reads)
    __builtin_amdgcn_s_setprio(1);
#pragma unroll
    for (int nc = 0; nc < 4; ++nc) {
      int row0 = nc * 16 + l15;
      f16x8 v0 = *reinterpret_cast<const f16x8*>(&Vcur[row0 * 64 + ((8 * lhi) ^ ((row0 & 7) << 3))]);
      f16x8 v1 = *reinterpret_cast<const f16x8*>(&Vcur[row0 * 64 + ((32 + 8 * lhi) ^ ((row0 & 7) << 3))]);
      oa[nc] = mfma16x16x32(pa0, v0, oa[nc]);
      oa[nc] = mfma16x16x32(pa1, v1, oa[nc]);
    }
    __builtin_amdgcn_s_setprio(0);

    // stage next V tile into the other buffer (safe: Vnxt last read before the
    // barrier that ended iter t-1), then one barrier for the whole iteration
    WRITEV(Vnxt);
    __syncthreads();
  }

  const int orow0 = b * T + t0;
#pragma unroll
  for (int nc = 0; nc < 4; ++nc) {
#pragma unroll
    for (int i = 0; i < 4; ++i) {
      int m = 4 * lhi + i;
      float inv = 1.0f / l_r[i];
      outh[(size_t)(orow0 + m) * 1024 + h * 64 + nc * 16 + l15] = (f16)(oa[nc][i] * inv);
    }
  }
#undef LOADK
#undef LOADV
#undef WRITEV
}

extern "C" void kernel_launch(void* const* d_in, const int* in_sizes, int n_in,
                              void* d_out, int out_size, void* d_ws, size_t ws_size,
                              hipStream_t stream) {
  const float* x      = (const float*)d_in[0];  // [2,2048,1024]
  const float* w_qkv  = (const float*)d_in[1];  // [1024,3072]
  const float* b_qkv  = (const float*)d_in[2];  // [3072]
  const float* w_out  = (const float*)d_in[3];  // [1024,1024]
  const float* b_out  = (const float*)d_in[4];  // [1024]
  float* out = (float*)d_out;                   // [2,2048,1024] f32

  char* ws = (char*)d_ws;
  f16* xh    = (f16*)(ws);                 //  8 MB: x as f16 [4096][1024]
  f16* wqkvT = (f16*)(ws + 8388608);       //  6 MB: w_qkv^T [3072][1024]
  f16* woutT = (f16*)(ws + 14680064);      //  2 MB: w_out^T [1024][1024]
  f16* qkvh  = (f16*)(ws + 16777216);      // 24 MB: qkv [4096][3072] (Q pre-scaled)
  f16* attnh = (f16*)(ws + 41943040);      //  8 MB: attention out [4096][1024]

  cvt_f32_f16<<<4096, 256, 0, stream>>>(x, xh, 1048576);
  transpose_cvt<<<dim3(96, 32), 256, 0, stream>>>(w_qkv, wqkvT, 1024, 3072);
  transpose_cvt<<<dim3(32, 32), 256, 0, stream>>>(w_out, woutT, 1024, 1024);
  gemm_bt<true><<<dim3(32, 24), 256, 0, stream>>>(xh, wqkvT, b_qkv, qkvh, nullptr,
                                                  4096, 3072, 1024);
  attn_kernel<<<1024, 256, 0, stream>>>(qkvh, attnh);
  gemm_bt<false><<<dim3(32, 8), 256, 0, stream>>>(attnh, woutT, b_out, nullptr, out,
                                                  4096, 1024, 1024);
}

// Round 5
// 166.960 us; speedup vs baseline: 1.4953x; 1.3923x over previous
//
#include <hip/hip_runtime.h>

typedef _Float16 f16;
typedef _Float16 f16x8 __attribute__((ext_vector_type(8)));
typedef _Float16 f16x4 __attribute__((ext_vector_type(4)));
typedef float f32x4 __attribute__((ext_vector_type(4)));
typedef float f32x16 __attribute__((ext_vector_type(16)));
typedef unsigned int u32x4 __attribute__((ext_vector_type(4)));

#define SCALE_Q 0.125f   // HEAD_DIM=64 -> 64^-0.5

__device__ __forceinline__ f32x4 mfma16x16x32(f16x8 a, f16x8 b, f32x4 c) {
  return __builtin_amdgcn_mfma_f32_16x16x32_f16(a, b, c, 0, 0, 0);
}
__device__ __forceinline__ f32x16 mfma32x32x16(f16x8 a, f16x8 b, f32x16 c) {
  return __builtin_amdgcn_mfma_f32_32x32x16_f16(a, b, c, 0, 0, 0);
}

typedef const __attribute__((address_space(1))) void* gptr1;
typedef __attribute__((address_space(3))) void* lptr3;
__device__ __forceinline__ void gload_lds16(const void* g, void* l) {
  __builtin_amdgcn_global_load_lds((gptr1)g, (lptr3)l, 16, 0, 0);
}

__device__ __forceinline__ unsigned pk2(float a, float b) {
  return __builtin_bit_cast(unsigned, __builtin_amdgcn_cvt_pkrtz(a, b));
}

// ---------------- f32 -> f16 elementwise convert (x) ----------------
__global__ __launch_bounds__(256)
void cvt_f32_f16(const float* __restrict__ in, f16* __restrict__ out, int n4) {
  int i = blockIdx.x * 256 + threadIdx.x;
  if (i >= n4) return;
  float4 v = reinterpret_cast<const float4*>(in)[i];
  f16x4 o = {(f16)v.x, (f16)v.y, (f16)v.z, (f16)v.w};
  reinterpret_cast<f16x4*>(out)[i] = o;
}

// ---------------- transpose + convert: in[R][Cin] f32 -> out[Cin][R] f16 ----------------
__global__ __launch_bounds__(256)
void transpose_cvt(const float* __restrict__ in, f16* __restrict__ out, int R, int Cin) {
  __shared__ float tile[32][33];
  int bx = blockIdx.x * 32;
  int by = blockIdx.y * 32;
  int tx = threadIdx.x & 31, ty = threadIdx.x >> 5;
#pragma unroll
  for (int i = ty; i < 32; i += 8)
    tile[i][tx] = in[(size_t)(by + i) * Cin + bx + tx];
  __syncthreads();
#pragma unroll
  for (int i = ty; i < 32; i += 8)
    out[(size_t)(bx + i) * R + by + tx] = (f16)tile[tx][i];
}

// ---------------- GEMM: C[M][N] = A[M][K] * Bt[N][K]^T, fused epilogue ----------------
template<bool QKV_EPI>
__global__ __launch_bounds__(256)
void gemm_bt(const f16* __restrict__ A, const f16* __restrict__ Bt,
             const float* __restrict__ bias, f16* __restrict__ outh,
             float* __restrict__ outf, int M, int N, int K) {
  constexpr int BM = 128, BN = 128, BK = 32;
  __shared__ f16 As[BM * BK];
  __shared__ f16 Bs[BN * BK];
  const int tid = threadIdx.x;
  const int l = tid & 63;
  const int w = tid >> 6;
  const int wr = w >> 1, wc = w & 1;
  const int bm = blockIdx.x * BM, bn = blockIdx.y * BN;
  const int l15 = l & 15, lhi = l >> 4;

  f32x4 acc[4][4] = {};

  const char* Ab = (const char*)A;
  const char* Bb = (const char*)Bt;
  const size_t rowbytes = (size_t)K * 2;

  for (int kt = 0; kt < K; kt += BK) {
    __syncthreads();
#pragma unroll
    for (int c = 0; c < 2; ++c) {
      int o = tid * 16 + c * 4096;
      int r = o >> 6;
      int cb = o & 63;
      gload_lds16(Ab + (size_t)(bm + r) * rowbytes + (size_t)kt * 2 + cb, (char*)As + o);
      gload_lds16(Bb + (size_t)(bn + r) * rowbytes + (size_t)kt * 2 + cb, (char*)Bs + o);
    }
    __syncthreads();

    f16x8 af[4], bf[4];
#pragma unroll
    for (int i = 0; i < 4; ++i)
      af[i] = *reinterpret_cast<const f16x8*>(&As[(wr * 64 + i * 16 + l15) * BK + 8 * lhi]);
#pragma unroll
    for (int i = 0; i < 4; ++i)
      bf[i] = *reinterpret_cast<const f16x8*>(&Bs[(wc * 64 + i * 16 + l15) * BK + 8 * lhi]);
#pragma unroll
    for (int i = 0; i < 4; ++i)
#pragma unroll
      for (int j = 0; j < 4; ++j)
        acc[i][j] = mfma16x16x32(af[i], bf[j], acc[i][j]);
  }

#pragma unroll
  for (int i = 0; i < 4; ++i) {
#pragma unroll
    for (int j = 0; j < 4; ++j) {
      int gr0 = bm + wr * 64 + i * 16 + 4 * lhi;
      int gc = bn + wc * 64 + j * 16 + l15;
      float b = bias[gc];
#pragma unroll
      for (int r = 0; r < 4; ++r) {
        float v = acc[i][j][r] + b;
        if constexpr (QKV_EPI) {
          if (gc < 1024) v *= SCALE_Q;
          outh[(size_t)(gr0 + r) * N + gc] = (f16)v;
        } else {
          outf[(size_t)(gr0 + r) * N + gc] = v;
        }
      }
    }
  }
}

// ---------------- flash attention v3b: 32x32 swapped-operand, lane-local softmax ----
// qkv[4096][3072] f16: row = b*2048+t; cols [0,1024)=Q(pre-scaled), [1024,2048)=K, [2048,3072)=V
// out: attnh[4096][1024] f16, col = h*64+d
// Per wave: 32 q-rows (q = lane&31). S^T tiles via mfma(K,Q): lane holds 32 of 64
// keys for its q-row (C/D row = (r&3)+8*(r>>2)+4*hi). O^T via mfma(V^T, P^T): col=q
// lane-local -> scalar rescale. P^T words exchanged across lane halves via shfl_xor(32).
__global__ __launch_bounds__(256)
void attn_kernel(const f16* __restrict__ qkv, f16* __restrict__ outh) {
  constexpr int T = 2048;
  constexpr int ROW = 3072;
  __shared__ f16 Vt[2][64 * 64];   // [buf][d][key] transposed V, XOR-swizzled

  const int tid = threadIdx.x;
  const int l = tid & 63;
  const int w = tid >> 6;
  const int l31 = l & 31, hi = l >> 5;

  // (b,h) pair in LOW bits -> one XCD serves all q-tiles of 4 pairs (2MB K+V in L2)
  const int bid = blockIdx.x;
  const int p = bid & 31;
  const int b = p >> 4;
  const int h = p & 15;
  const int qt = bid >> 5;          // 0..15; 128 q-rows per block

  const size_t base = (size_t)b * T * ROW;
  const int q0 = qt * 128 + w * 32;

  // Q fragments (B-operand): bq[kd] = Q[q0+l31][16kd + 8hi .. +7]  (pre-scaled)
  f16x8 bq[4];
  {
    const f16* qp = qkv + base + (size_t)(q0 + l31) * ROW + h * 64 + hi * 8;
#pragma unroll
    for (int kd = 0; kd < 4; ++kd)
      bq[kd] = *reinterpret_cast<const f16x8*>(qp + kd * 16);
  }

  const f16* Kb = qkv + base + 1024 + h * 64;
  const f16* Vb = qkv + base + 2048 + h * 64;

  f32x16 o0 = {}, o1 = {};
  float m_r = -1e30f, l_r = 0.f;

  // V staging assignment: thread stages key vt_t, d-range [vt_d0, vt_d0+16)
  const int vt_t = tid & 63;
  const int vt_d0 = (tid >> 6) * 16;

  f16x8 ak[2][4];   // K fragments (A-operand), current tile
  f16x8 vr0, vr1;   // staged V rows for next tile

#define LOADK(KV)                                                              \
  do {                                                                         \
    _Pragma("unroll") for (int kt = 0; kt < 2; ++kt)                           \
    _Pragma("unroll") for (int kd = 0; kd < 4; ++kd)                           \
      ak[kt][kd] = *reinterpret_cast<const f16x8*>(                            \
          Kb + (size_t)((KV) + kt * 32 + l31) * ROW + kd * 16 + hi * 8);       \
  } while (0)

#define LOADV(KV)                                                              \
  do {                                                                         \
    const f16* vp = Vb + (size_t)((KV) + vt_t) * ROW + vt_d0;                  \
    vr0 = *reinterpret_cast<const f16x8*>(vp);                                 \
    vr1 = *reinterpret_cast<const f16x8*>(vp + 8);                             \
  } while (0)

#define WRITEV(DST)                                                            \
  do {                                                                         \
    _Pragma("unroll") for (int j = 0; j < 8; ++j) {                            \
      int r0 = vt_d0 + j, r1 = vt_d0 + 8 + j;                                  \
      (DST)[r0 * 64 + (vt_t ^ ((r0 & 7) << 3))] = vr0[j];                      \
      (DST)[r1 * 64 + (vt_t ^ ((r1 & 7) << 3))] = vr1[j];                      \
    }                                                                          \
  } while (0)

  LOADK(0);
  LOADV(0);
  WRITEV(&Vt[0][0]);
  __syncthreads();

  for (int t = 0; t < 32; ++t) {
    const int kv = t * 64;
    const int nkv = (t < 31) ? kv + 64 : kv;
    f16* Vcur = &Vt[t & 1][0];
    f16* Vnxt = &Vt[(t & 1) ^ 1][0];

    LOADV(nkv);   // issue next V early; consumed at WRITEV below

    // S^T tiles: s_kt[r] = S[key = kv+32kt+(r&3)+8(r>>2)+4hi][q = l31]
    f32x16 s0 = {}, s1 = {};
    __builtin_amdgcn_s_setprio(1);
#pragma unroll
    for (int kd = 0; kd < 4; ++kd) s0 = mfma32x32x16(ak[0][kd], bq[kd], s0);
#pragma unroll
    for (int kd = 0; kd < 4; ++kd) s1 = mfma32x32x16(ak[1][kd], bq[kd], s1);
    __builtin_amdgcn_s_setprio(0);

    LOADK(nkv);   // K regs free -> prefetch next tile

    // --- lane-local online softmax (q = l31) ---
    float mx[16];
#pragma unroll
    for (int r = 0; r < 16; ++r) mx[r] = fmaxf(s0[r], s1[r]);
#pragma unroll
    for (int st = 8; st > 0; st >>= 1)
#pragma unroll
      for (int r = 0; r < st; ++r) mx[r] = fmaxf(mx[r], mx[r + st]);
    float tm = fmaxf(mx[0], __shfl_xor(mx[0], 32));   // combine with lane^32 half
    float mnew = fmaxf(m_r, tm);
    float scl = __expf(m_r - mnew);

    float sm[16];
#pragma unroll
    for (int r = 0; r < 16; ++r) {
      s0[r] = __expf(s0[r] - mnew);
      s1[r] = __expf(s1[r] - mnew);
      sm[r] = s0[r] + s1[r];
    }
#pragma unroll
    for (int st = 8; st > 0; st >>= 1)
#pragma unroll
      for (int r = 0; r < st; ++r) sm[r] += sm[r + st];
    float rs = sm[0] + __shfl_xor(sm[0], 32);
    l_r = l_r * scl + rs;
    m_r = mnew;
#pragma unroll
    for (int r = 0; r < 16; ++r) { o0[r] *= scl; o1[r] *= scl; }

    // --- P^T fragments: pack pairs, exchange across lane halves via shfl_xor(32) ---
    // Own words (within 16-key block, local key base 4*hi):
    //   wB(u): keys {4hi+2u, 4hi+2u+1}      (from s regs r = 8*s2 + 2u + {0,1})
    //   wA(u): keys {8+4hi+2u, 8+4hi+2u+1}  (from s regs r = 8*s2+4+2u + {0,1})
    // Target: element j of bp[ks] = key 8*hi + j  ->  word j2 keys {8hi+2j2, +1}:
    //   hi=0: wd[u] = own wB(u)      {2u,2u+1};   wd[2+u] = partner wB(u) {4+2u,..}
    //   hi=1: wd[u] = partner wA(u)  {8+2u,..};   wd[2+u] = own wA(u)    {12+2u,..}
    f16x8 bp[4];
#pragma unroll
    for (int kt = 0; kt < 2; ++kt) {
#pragma unroll
      for (int s2 = 0; s2 < 2; ++s2) {
        u32x4 wd;
#pragma unroll
        for (int u = 0; u < 2; ++u) {
          float a0 = kt ? s1[8 * s2 + 2 * u] : s0[8 * s2 + 2 * u];
          float a1 = kt ? s1[8 * s2 + 2 * u + 1] : s0[8 * s2 + 2 * u + 1];
          float b0 = kt ? s1[8 * s2 + 4 + 2 * u] : s0[8 * s2 + 4 + 2 * u];
          float b1 = kt ? s1[8 * s2 + 4 + 2 * u + 1] : s0[8 * s2 + 4 + 2 * u + 1];
          unsigned wB = pk2(a0, a1);
          unsigned wA = pk2(b0, b1);
          unsigned oB = __shfl_xor(wB, 32);
          unsigned oA = __shfl_xor(wA, 32);
          wd[u]     = hi ? oA : wB;
          wd[2 + u] = hi ? wA : oB;
        }
        bp[2 * kt + s2] = __builtin_bit_cast(f16x8, wd);
      }
    }

    // --- O^T += V^T x P^T  (A = V^T from swizzled LDS, B = P^T) ---
    __builtin_amdgcn_s_setprio(1);
#pragma unroll
    for (int ks = 0; ks < 4; ++ks) {
      int row0 = l31;
      int c = ks * 16 + hi * 8;
      f16x8 av0 = *reinterpret_cast<const f16x8*>(&Vcur[row0 * 64 + (c ^ ((row0 & 7) << 3))]);
      o0 = mfma32x32x16(av0, bp[ks], o0);
      int row1 = 32 + l31;
      f16x8 av1 = *reinterpret_cast<const f16x8*>(&Vcur[row1 * 64 + (c ^ ((row1 & 7) << 3))]);
      o1 = mfma32x32x16(av1, bp[ks], o1);
    }
    __builtin_amdgcn_s_setprio(0);

    WRITEV(Vnxt);
    __syncthreads();
  }

  // epilogue: lane holds O^T col q = l31; rows d = (r&3)+8*(r>>2)+4hi (+32 for o1)
  const float inv = 1.0f / l_r;
  f16* orow = outh + (size_t)(b * T + q0 + l31) * 1024 + h * 64;
#pragma unroll
  for (int r = 0; r < 16; ++r) {
    int d = (r & 3) + 8 * (r >> 2) + 4 * hi;
    orow[d] = (f16)(o0[r] * inv);
    orow[32 + d] = (f16)(o1[r] * inv);
  }
#undef LOADK
#undef LOADV
#undef WRITEV
}

extern "C" void kernel_launch(void* const* d_in, const int* in_sizes, int n_in,
                              void* d_out, int out_size, void* d_ws, size_t ws_size,
                              hipStream_t stream) {
  const float* x      = (const float*)d_in[0];  // [2,2048,1024]
  const float* w_qkv  = (const float*)d_in[1];  // [1024,3072]
  const float* b_qkv  = (const float*)d_in[2];  // [3072]
  const float* w_out  = (const float*)d_in[3];  // [1024,1024]
  const float* b_out  = (const float*)d_in[4];  // [1024]
  float* out = (float*)d_out;                   // [2,2048,1024] f32

  char* ws = (char*)d_ws;
  f16* xh    = (f16*)(ws);                 //  8 MB: x as f16 [4096][1024]
  f16* wqkvT = (f16*)(ws + 8388608);       //  6 MB: w_qkv^T [3072][1024]
  f16* woutT = (f16*)(ws + 14680064);      //  2 MB: w_out^T [1024][1024]
  f16* qkvh  = (f16*)(ws + 16777216);      // 24 MB: qkv [4096][3072] (Q pre-scaled)
  f16* attnh = (f16*)(ws + 41943040);      //  8 MB: attention out [4096][1024]

  cvt_f32_f16<<<4096, 256, 0, stream>>>(x, xh, 1048576);
  transpose_cvt<<<dim3(96, 32), 256, 0, stream>>>(w_qkv, wqkvT, 1024, 3072);
  transpose_cvt<<<dim3(32, 32), 256, 0, stream>>>(w_out, woutT, 1024, 1024);
  gemm_bt<true><<<dim3(32, 24), 256, 0, stream>>>(xh, wqkvT, b_qkv, qkvh, nullptr,
                                                  4096, 3072, 1024);
  attn_kernel<<<512, 256, 0, stream>>>(qkvh, attnh);
  gemm_bt<false><<<dim3(32, 8), 256, 0, stream>>>(attnh, woutT, b_out, nullptr, out,
                                                  4096, 1024, 1024);
}